// Round 3
// baseline (429.912 us; speedup 1.0000x reference)
//
#include <hip/hip_runtime.h>
#include <math.h>

typedef __attribute__((ext_vector_type(8))) short v8s;
typedef __attribute__((ext_vector_type(4))) float v4f;
typedef __attribute__((ext_vector_type(4))) unsigned int v4u;
typedef __attribute__((ext_vector_type(2))) unsigned int v2u;

#define MFMA16(a,b,c) __builtin_amdgcn_mfma_f32_16x16x32_bf16(a,b,c,0,0,0)

__device__ __forceinline__ unsigned short f2b(float f){
  unsigned u = __builtin_bit_cast(unsigned, f);
  u += 0x7FFFu + ((u>>16)&1u);
  return (unsigned short)(u>>16);
}
__device__ __forceinline__ float gelu_exact(float x){
  return 0.5f*x*(1.0f + erff(x*0.70710678118654752f));
}

// ---------------- LayerNorm (ddof=1, sd+eps) -> bf16 out ----------------
__global__ __launch_bounds__(256) void ln_kernel(const float* __restrict__ x,
    const float* __restrict__ alpha, const float* __restrict__ bias,
    unsigned short* __restrict__ out)
{
  const int D = 1024;
  int row = blockIdx.x;
  int tid = threadIdx.x;
  const float* xr = x + (size_t)row*D;
  v4f v = ((const v4f*)xr)[tid];
  float s  = v[0]+v[1]+v[2]+v[3];
  float s2 = v[0]*v[0]+v[1]*v[1]+v[2]*v[2]+v[3]*v[3];
  #pragma unroll
  for (int off=1; off<64; off<<=1){ s += __shfl_xor(s, off); s2 += __shfl_xor(s2, off); }
  __shared__ float red[8];
  int w = tid>>6;
  if ((tid&63)==0){ red[w]=s; red[4+w]=s2; }
  __syncthreads();
  s  = red[0]+red[1]+red[2]+red[3];
  s2 = red[4]+red[5]+red[6]+red[7];
  float mu  = s*(1.0f/D);
  float var = (s2 - (float)D*mu*mu)*(1.0f/(D-1));
  float inv = 1.0f/(sqrtf(fmaxf(var,0.0f)) + 1e-6f);
  v4f a  = ((const v4f*)alpha)[tid];
  v4f bi = ((const v4f*)bias)[tid];
  unsigned short o[4];
  #pragma unroll
  for (int i=0;i<4;i++) o[i] = f2b(a[i]*(v[i]-mu)*inv + bi[i]);
  v2u pk; pk[0] = (unsigned)o[0] | ((unsigned)o[1]<<16);
          pk[1] = (unsigned)o[2] | ((unsigned)o[3]<<16);
  ((v2u*)(out + (size_t)row*D))[tid] = pk;
}

// ---------------- f32 [K][N] -> bf16 [N][K] transpose ----------------
__global__ __launch_bounds__(256) void transpose_f2b(const float* __restrict__ in,
    unsigned short* __restrict__ out, int K, int N)
{
  __shared__ float t[32][33];
  int n0 = blockIdx.x*32, k0 = blockIdx.y*32;
  int tx = threadIdx.x, ty = threadIdx.y;
  #pragma unroll
  for (int j=0;j<4;j++) t[ty+8*j][tx] = in[(size_t)(k0+ty+8*j)*N + n0+tx];
  __syncthreads();
  #pragma unroll
  for (int j=0;j<4;j++) out[(size_t)(n0+ty+8*j)*K + k0+tx] = f2b(t[tx][ty+8*j]);
}

// ---------------- GEMM: C[M][N] = A[M][K] * Bt[N][K]^T (+bias, epilogue) ----
// MODE 0: outb = bf16(acc+bias)
// MODE 1: outf = acc+bias+res
// MODE 2: outb = bf16(gelu(acc+bias))
// MODE 3: outf = gelu(acc+bias)+res
template<int MODE>
__global__ __launch_bounds__(256) void gemm_bt(
    const unsigned short* __restrict__ A, const unsigned short* __restrict__ Bt,
    const float* __restrict__ bias, const float* __restrict__ res,
    unsigned short* __restrict__ outb, float* __restrict__ outf,
    int M, int N, int K)
{
  __shared__ unsigned short As[128][40];  // stride 40 bf16 = 80 B (16B-aligned)
  __shared__ unsigned short Bs[128][40];
  int m0 = blockIdx.x*128, n0 = blockIdx.y*128;
  int tid = threadIdx.x;
  int w = tid>>6, l = tid&63;
  int wm = (w>>1)*64, wn = (w&1)*64;
  int r16 = l&15, kq = l>>4;
  v4f acc[4][4] = {};
  int sr = tid>>2, sc = (tid&3)*8;
  const unsigned short* Ap = A  + (size_t)(m0+sr)*K + sc;
  const unsigned short* Bp = Bt + (size_t)(n0+sr)*K + sc;
  for (int kb=0; kb<K; kb+=32){
    v4u va0 = *(const v4u*)(Ap + kb);
    v4u va1 = *(const v4u*)(Ap + (size_t)64*K + kb);
    v4u vb0 = *(const v4u*)(Bp + kb);
    v4u vb1 = *(const v4u*)(Bp + (size_t)64*K + kb);
    __syncthreads();
    *(v4u*)&As[sr   ][sc] = va0;
    *(v4u*)&As[sr+64][sc] = va1;
    *(v4u*)&Bs[sr   ][sc] = vb0;
    *(v4u*)&Bs[sr+64][sc] = vb1;
    __syncthreads();
    v8s a[4], b[4];
    #pragma unroll
    for (int mi=0;mi<4;mi++) a[mi] = *(const v8s*)&As[wm+mi*16+r16][kq*8];
    #pragma unroll
    for (int ni=0;ni<4;ni++) b[ni] = *(const v8s*)&Bs[wn+ni*16+r16][kq*8];
    #pragma unroll
    for (int mi=0;mi<4;mi++)
      #pragma unroll
      for (int ni=0;ni<4;ni++)
        acc[mi][ni] = MFMA16(a[mi], b[ni], acc[mi][ni]);
  }
  #pragma unroll
  for (int mi=0;mi<4;mi++){
    #pragma unroll
    for (int ni=0;ni<4;ni++){
      int col = n0 + wn + ni*16 + r16;
      float bv = bias[col];
      #pragma unroll
      for (int r=0;r<4;r++){
        int row = m0 + wm + mi*16 + kq*4 + r;
        float t = acc[mi][ni][r] + bv;
        if (MODE==2 || MODE==3) t = gelu_exact(t);
        if (MODE==0 || MODE==2) outb[(size_t)row*N + col] = f2b(t);
        else                    outf[(size_t)row*N + col] = t + res[(size_t)row*N + col];
      }
    }
  }
}

// ---------------- flash attention: 1 block = (b,h,128 q-rows) ----------------
__global__ __launch_bounds__(256) void attn_kernel(
    const unsigned short* __restrict__ Q, const unsigned short* __restrict__ Kb,
    const unsigned short* __restrict__ Vb, const int* __restrict__ mask,
    unsigned short* __restrict__ out)
{
  const int S = 2048, D = 1024;
  __shared__ unsigned short Ks[64][72];     // [k_row][dk], pad->72 (144B, aligned)
  __shared__ unsigned short Vt[64][72];     // [dk][k_row] transposed
  __shared__ unsigned short Ps[4][32][72];  // per-wave P tile [q][k]
  int bh = blockIdx.x >> 4;
  int qt = blockIdx.x & 15;
  int b = bh >> 4, h = bh & 15;
  int tid = threadIdx.x, w = tid>>6, l = tid&63;
  int r16 = l&15, kq = l>>4;
  size_t base = (size_t)b*S*D + h*64;
  const unsigned short* Qp = Q  + base;
  const unsigned short* Kp = Kb + base;
  const unsigned short* Vp = Vb + base;
  int qbase = qt*128 + w*32;
  v8s qf[2][2];
  #pragma unroll
  for (int mi=0;mi<2;mi++)
    #pragma unroll
    for (int ks=0;ks<2;ks++)
      qf[mi][ks] = *(const v8s*)(Qp + (size_t)(qbase+mi*16+r16)*D + ks*32 + kq*8);
  float m_run[2][4], l_run[2][4];
  v4f o[2][4] = {};
  #pragma unroll
  for (int mi=0;mi<2;mi++)
    #pragma unroll
    for (int r=0;r<4;r++){ m_run[mi][r] = -1e30f; l_run[mi][r] = 0.0f; }
  const int* mp = mask + (size_t)b*S*S;
  int sr = tid>>3, sc = (tid&7)*8;
  for (int kt=0; kt<S; kt+=64){
    v4u k0 = *(const v4u*)(Kp + (size_t)(kt+sr   )*D + sc);
    v4u k1 = *(const v4u*)(Kp + (size_t)(kt+sr+32)*D + sc);
    v4u v0 = *(const v4u*)(Vp + (size_t)(kt+sr   )*D + sc);
    v4u v1 = *(const v4u*)(Vp + (size_t)(kt+sr+32)*D + sc);
    __syncthreads();
    *(v4u*)&Ks[sr   ][sc] = k0;
    *(v4u*)&Ks[sr+32][sc] = k1;
    {
      const unsigned short* p0 = (const unsigned short*)&v0;
      const unsigned short* p1 = (const unsigned short*)&v1;
      #pragma unroll
      for (int j=0;j<8;j++){ Vt[sc+j][sr] = p0[j]; Vt[sc+j][sr+32] = p1[j]; }
    }
    __syncthreads();
    v4f s[2][4] = {};
    #pragma unroll
    for (int ks=0;ks<2;ks++){
      v8s kf[4];
      #pragma unroll
      for (int nj=0;nj<4;nj++) kf[nj] = *(const v8s*)&Ks[nj*16+r16][ks*32+kq*8];
      #pragma unroll
      for (int mi=0;mi<2;mi++)
        #pragma unroll
        for (int nj=0;nj<4;nj++)
          s[mi][nj] = MFMA16(qf[mi][ks], kf[nj], s[mi][nj]);
    }
    // mask + scale (reference: where(mask==0, -1e9, scores/8))
    #pragma unroll
    for (int mi=0;mi<2;mi++)
      #pragma unroll
      for (int nj=0;nj<4;nj++){
        int kcol = kt + nj*16 + r16;
        #pragma unroll
        for (int r=0;r<4;r++){
          int qrow = qbase + mi*16 + kq*4 + r;
          int mv = mp[(size_t)qrow*S + kcol];
          s[mi][nj][r] = mv ? s[mi][nj][r]*0.125f : -1e9f;
        }
      }
    // online softmax
    float corr[2][4];
    #pragma unroll
    for (int mi=0;mi<2;mi++)
      #pragma unroll
      for (int r=0;r<4;r++){
        float t = fmaxf(fmaxf(s[mi][0][r], s[mi][1][r]), fmaxf(s[mi][2][r], s[mi][3][r]));
        t = fmaxf(t, __shfl_xor(t,1));
        t = fmaxf(t, __shfl_xor(t,2));
        t = fmaxf(t, __shfl_xor(t,4));
        t = fmaxf(t, __shfl_xor(t,8));
        float mn = fmaxf(m_run[mi][r], t);
        corr[mi][r] = expf(m_run[mi][r] - mn);
        m_run[mi][r] = mn;
      }
    #pragma unroll
    for (int mi=0;mi<2;mi++)
      #pragma unroll
      for (int r=0;r<4;r++){
        float rs = 0.0f;
        #pragma unroll
        for (int nj=0;nj<4;nj++){
          float p = expf(s[mi][nj][r] - m_run[mi][r]);
          s[mi][nj][r] = p;
          rs += p;
        }
        rs += __shfl_xor(rs,1); rs += __shfl_xor(rs,2);
        rs += __shfl_xor(rs,4); rs += __shfl_xor(rs,8);
        l_run[mi][r] = l_run[mi][r]*corr[mi][r] + rs;
        #pragma unroll
        for (int nj=0;nj<4;nj++) o[mi][nj][r] *= corr[mi][r];
      }
    // P -> LDS (bf16) for A-fragment relayout
    #pragma unroll
    for (int mi=0;mi<2;mi++)
      #pragma unroll
      for (int nj=0;nj<4;nj++)
        #pragma unroll
        for (int r=0;r<4;r++)
          Ps[w][mi*16+kq*4+r][nj*16+r16] = f2b(s[mi][nj][r]);
    // PV
    #pragma unroll
    for (int ks=0;ks<2;ks++){
      v8s pa[2], vv[4];
      #pragma unroll
      for (int mi=0;mi<2;mi++) pa[mi] = *(const v8s*)&Ps[w][mi*16+r16][ks*32+kq*8];
      #pragma unroll
      for (int nj=0;nj<4;nj++) vv[nj] = *(const v8s*)&Vt[nj*16+r16][ks*32+kq*8];
      #pragma unroll
      for (int mi=0;mi<2;mi++)
        #pragma unroll
        for (int nj=0;nj<4;nj++)
          o[mi][nj] = MFMA16(pa[mi], vv[nj], o[mi][nj]);
    }
  }
  #pragma unroll
  for (int mi=0;mi<2;mi++)
    #pragma unroll
    for (int r=0;r<4;r++){
      float invl = 1.0f / l_run[mi][r];
      int qrow = qbase + mi*16 + kq*4 + r;
      #pragma unroll
      for (int nj=0;nj<4;nj++)
        out[(size_t)(b*S+qrow)*D + h*64 + nj*16 + r16] = f2b(o[mi][nj][r]*invl);
    }
}

// ---------------- launcher ----------------
extern "C" void kernel_launch(void* const* d_in, const int* in_sizes, int n_in,
                              void* d_out, int out_size, void* d_ws, size_t ws_size,
                              hipStream_t stream)
{
  const int D=1024, DFF=2048, BS=4096, S=2048;
  const float* x      = (const float*)d_in[0];
  const int*   mask   = (const int*)d_in[1];
  const float* alpha1 = (const float*)d_in[2];
  const float* bias1  = (const float*)d_in[3];
  const float* Wq     = (const float*)d_in[4];
  const float* bq     = (const float*)d_in[5];
  const float* Wk     = (const float*)d_in[6];
  const float* bk     = (const float*)d_in[7];
  const float* Wv     = (const float*)d_in[8];
  const float* bv     = (const float*)d_in[9];
  const float* Wo     = (const float*)d_in[10];
  const float* bo     = (const float*)d_in[11];
  const float* alpha2 = (const float*)d_in[12];
  const float* bias2  = (const float*)d_in[13];
  const float* W1     = (const float*)d_in[14];
  const float* b1     = (const float*)d_in[15];
  const float* W2     = (const float*)d_in[16];
  const float* b2     = (const float*)d_in[17];
  float* outp = (float*)d_out;

  char* ws = (char*)d_ws;
  size_t off = 0;
  auto alloc = [&](size_t bytes){ void* p = ws+off; off += (bytes+255)&~(size_t)255; return p; };
  unsigned short* x2b   = (unsigned short*)alloc((size_t)BS*D*2);
  unsigned short* qB    = (unsigned short*)alloc((size_t)BS*D*2);
  unsigned short* kB    = (unsigned short*)alloc((size_t)BS*D*2);
  unsigned short* vB    = (unsigned short*)alloc((size_t)BS*D*2);
  unsigned short* attnB = (unsigned short*)alloc((size_t)BS*D*2);
  unsigned short* h1    = (unsigned short*)alloc((size_t)BS*DFF*2);
  float*          xres  = (float*)alloc((size_t)BS*D*4);
  unsigned short* wqT   = (unsigned short*)alloc((size_t)D*D*2);
  unsigned short* wkT   = (unsigned short*)alloc((size_t)D*D*2);
  unsigned short* wvT   = (unsigned short*)alloc((size_t)D*D*2);
  unsigned short* woT   = (unsigned short*)alloc((size_t)D*D*2);
  unsigned short* w1T   = (unsigned short*)alloc((size_t)D*DFF*2);
  unsigned short* w2T   = (unsigned short*)alloc((size_t)DFF*D*2);

  dim3 tb(32,8);
  transpose_f2b<<<dim3(D/32,  D/32 ), tb, 0, stream>>>(Wq, wqT, D, D);
  transpose_f2b<<<dim3(D/32,  D/32 ), tb, 0, stream>>>(Wk, wkT, D, D);
  transpose_f2b<<<dim3(D/32,  D/32 ), tb, 0, stream>>>(Wv, wvT, D, D);
  transpose_f2b<<<dim3(D/32,  D/32 ), tb, 0, stream>>>(Wo, woT, D, D);
  transpose_f2b<<<dim3(DFF/32,D/32 ), tb, 0, stream>>>(W1, w1T, D, DFF);
  transpose_f2b<<<dim3(D/32,  DFF/32), tb, 0, stream>>>(W2, w2T, DFF, D);

  ln_kernel<<<BS, 256, 0, stream>>>(x, alpha1, bias1, x2b);

  gemm_bt<0><<<dim3(BS/128, D/128), 256, 0, stream>>>(x2b, wqT, bq, nullptr, qB, nullptr, BS, D, D);
  gemm_bt<0><<<dim3(BS/128, D/128), 256, 0, stream>>>(x2b, wkT, bk, nullptr, kB, nullptr, BS, D, D);
  gemm_bt<0><<<dim3(BS/128, D/128), 256, 0, stream>>>(x2b, wvT, bv, nullptr, vB, nullptr, BS, D, D);

  attn_kernel<<<512, 256, 0, stream>>>(qB, kB, vB, mask, attnB);

  gemm_bt<1><<<dim3(BS/128, D/128), 256, 0, stream>>>(attnB, woT, bo, x, nullptr, xres, BS, D, D);

  ln_kernel<<<BS, 256, 0, stream>>>(xres, alpha2, bias2, x2b);

  gemm_bt<2><<<dim3(BS/128, DFF/128), 256, 0, stream>>>(x2b, w1T, b1, nullptr, h1, nullptr, BS, DFF, D);
  gemm_bt<3><<<dim3(BS/128, D/128), 256, 0, stream>>>(h1, w2T, b2, xres, nullptr, outp, BS, D, DFF);
}

// Round 5
// 389.308 us; speedup vs baseline: 1.1043x; 1.1043x over previous
//
#include <hip/hip_runtime.h>
#include <math.h>

typedef __attribute__((ext_vector_type(8))) short v8s;
typedef __attribute__((ext_vector_type(4))) float v4f;
typedef __attribute__((ext_vector_type(4))) unsigned int v4u;
typedef __attribute__((ext_vector_type(2))) unsigned int v2u;

#define MFMA16(a,b,c) __builtin_amdgcn_mfma_f32_16x16x32_bf16(a,b,c,0,0,0)
#define QSCALE 0.18033688011112042f  /* 0.125 * log2(e) */

typedef const __attribute__((address_space(1))) void* gp1_t;
typedef __attribute__((address_space(3))) void* lp3_t;
__device__ __forceinline__ void gll16(const void* g, void* l){
  __builtin_amdgcn_global_load_lds((gp1_t)g, (lp3_t)l, 16, 0, 0);
}

__device__ __forceinline__ unsigned short f2b(float f){
  unsigned u = __builtin_bit_cast(unsigned, f);
  u += 0x7FFFu + ((u>>16)&1u);
  return (unsigned short)(u>>16);
}
__device__ __forceinline__ float gelu_exact(float x){
  return 0.5f*x*(1.0f + erff(x*0.70710678118654752f));
}

// ---------------- LayerNorm (ddof=1, sd+eps) -> bf16 out ----------------
__global__ __launch_bounds__(256) void ln_kernel(const float* __restrict__ x,
    const float* __restrict__ alpha, const float* __restrict__ bias,
    unsigned short* __restrict__ out)
{
  const int D = 1024;
  int row = blockIdx.x;
  int tid = threadIdx.x;
  const float* xr = x + (size_t)row*D;
  v4f v = ((const v4f*)xr)[tid];
  float s  = v[0]+v[1]+v[2]+v[3];
  float s2 = v[0]*v[0]+v[1]*v[1]+v[2]*v[2]+v[3]*v[3];
  #pragma unroll
  for (int off=1; off<64; off<<=1){ s += __shfl_xor(s, off); s2 += __shfl_xor(s2, off); }
  __shared__ float red[8];
  int w = tid>>6;
  if ((tid&63)==0){ red[w]=s; red[4+w]=s2; }
  __syncthreads();
  s  = red[0]+red[1]+red[2]+red[3];
  s2 = red[4]+red[5]+red[6]+red[7];
  float mu  = s*(1.0f/D);
  float var = (s2 - (float)D*mu*mu)*(1.0f/(D-1));
  float inv = 1.0f/(sqrtf(fmaxf(var,0.0f)) + 1e-6f);
  v4f a  = ((const v4f*)alpha)[tid];
  v4f bi = ((const v4f*)bias)[tid];
  unsigned short o[4];
  #pragma unroll
  for (int i=0;i<4;i++) o[i] = f2b(a[i]*(v[i]-mu)*inv + bi[i]);
  v2u pk; pk[0] = (unsigned)o[0] | ((unsigned)o[1]<<16);
          pk[1] = (unsigned)o[2] | ((unsigned)o[3]<<16);
  ((v2u*)(out + (size_t)row*D))[tid] = pk;
}

// ---------------- f32 [K][N] -> bf16 [N][K] transpose ----------------
__global__ __launch_bounds__(256) void transpose_f2b(const float* __restrict__ in,
    unsigned short* __restrict__ out, int K, int N)
{
  __shared__ float t[32][33];
  int n0 = blockIdx.x*32, k0 = blockIdx.y*32;
  int tx = threadIdx.x, ty = threadIdx.y;
  #pragma unroll
  for (int j=0;j<4;j++) t[ty+8*j][tx] = in[(size_t)(k0+ty+8*j)*N + n0+tx];
  __syncthreads();
  #pragma unroll
  for (int j=0;j<4;j++) out[(size_t)(n0+ty+8*j)*K + k0+tx] = f2b(t[tx][ty+8*j]);
}

// ---------------- mask -> per-(b, 64-qtile, 64-ktile) all-ones flags --------
__global__ __launch_bounds__(256) void mask_flags(const int* __restrict__ mask,
    unsigned char* __restrict__ flags)
{
  const int S = 2048;
  int bid = blockIdx.x;            // b*1024 + qt*32 + kt
  int kt = bid & 31, qt = (bid>>5)&31, b = bid>>10;
  int tid = threadIdx.x;
  const int* mp = mask + (size_t)b*S*S + (size_t)(qt*64)*S + kt*64;
  int ok = 1;
  #pragma unroll
  for (int i=0;i<16;i++){
    int idx = tid + i*256;
    int row = idx>>6, col = idx&63;
    ok &= (mp[(size_t)row*S + col] != 0);
  }
  ok = __all(ok) ? 1 : 0;
  __shared__ int f[4];
  if ((tid&63)==0) f[tid>>6] = ok;
  __syncthreads();
  if (tid==0) flags[bid] = (unsigned char)(f[0]&f[1]&f[2]&f[3]);
}

// ---------------- fused QKV GEMM: [4096]x[1024] @ [3072][1024]^T ------------
// global_load_lds staging, linear LDS. Q segment scaled by QSCALE.
__global__ __launch_bounds__(256) void gemm_qkv(
    const unsigned short* __restrict__ A, const unsigned short* __restrict__ Bt,
    const float* __restrict__ bq, const float* __restrict__ bk, const float* __restrict__ bv,
    unsigned short* __restrict__ qB, unsigned short* __restrict__ kB, unsigned short* __restrict__ vB)
{
  const int K = 1024, N = 1024;
  __shared__ unsigned short As[128][32];
  __shared__ unsigned short Bs[128][32];
  int m0 = blockIdx.x*128;
  int ny = blockIdx.y;              // 0..23
  int seg = ny>>3;                  // 0=q 1=k 2=v
  int n0g = ny*128;                 // row in Bt (3072 rows)
  int tid = threadIdx.x;
  int w = tid>>6, l = tid&63;
  int wm = (w>>1)*64, wn = (w&1)*64;
  int r16 = l&15, kq = l>>4;
  v4f acc[4][4] = {};
  int t4 = tid>>2, c8 = (tid&3)*8;
  const unsigned short* Ag = A  + (size_t)(m0 + t4)*K + c8;
  const unsigned short* Bg = Bt + (size_t)(n0g + t4)*K + c8;
  char* AsB = (char*)&As[0][0] + w*1024;
  char* BsB = (char*)&Bs[0][0] + w*1024;
  for (int kb=0; kb<K; kb+=32){
    __syncthreads();
    gll16(Ag + kb,                 AsB);
    gll16(Ag + (size_t)64*K + kb,  AsB + 4096);
    gll16(Bg + kb,                 BsB);
    gll16(Bg + (size_t)64*K + kb,  BsB + 4096);
    __syncthreads();
    v8s a[4], b[4];
    #pragma unroll
    for (int mi=0;mi<4;mi++) a[mi] = *(const v8s*)&As[wm+mi*16+r16][kq*8];
    #pragma unroll
    for (int ni=0;ni<4;ni++) b[ni] = *(const v8s*)&Bs[wn+ni*16+r16][kq*8];
    #pragma unroll
    for (int mi=0;mi<4;mi++)
      #pragma unroll
      for (int ni=0;ni<4;ni++)
        acc[mi][ni] = MFMA16(a[mi], b[ni], acc[mi][ni]);
  }
  unsigned short* ob = (seg==0) ? qB : (seg==1) ? kB : vB;
  const float*    bp = (seg==0) ? bq : (seg==1) ? bk : bv;
  float sc = (seg==0) ? QSCALE : 1.0f;
  int ncol0 = (ny&7)*128;
  #pragma unroll
  for (int mi=0;mi<4;mi++){
    #pragma unroll
    for (int ni=0;ni<4;ni++){
      int col = ncol0 + wn + ni*16 + r16;
      float bvv = bp[col];
      #pragma unroll
      for (int r=0;r<4;r++){
        int row = m0 + wm + mi*16 + kq*4 + r;
        ob[(size_t)row*N + col] = f2b((acc[mi][ni][r] + bvv)*sc);
      }
    }
  }
}

// ---------------- generic GEMM: C[M][N] = A[M][K] * Bt[N][K]^T --------------
// MODE 1: outf = acc+bias+res ; MODE 2: outb = bf16(gelu(acc+bias))
// MODE 3: outf = gelu(acc+bias)+res
template<int MODE>
__global__ __launch_bounds__(256) void gemm_bt(
    const unsigned short* __restrict__ A, const unsigned short* __restrict__ Bt,
    const float* __restrict__ bias, const float* __restrict__ res,
    unsigned short* __restrict__ outb, float* __restrict__ outf,
    int M, int N, int K)
{
  __shared__ unsigned short As[128][32];
  __shared__ unsigned short Bs[128][32];
  int m0 = blockIdx.x*128, n0 = blockIdx.y*128;
  int tid = threadIdx.x;
  int w = tid>>6, l = tid&63;
  int wm = (w>>1)*64, wn = (w&1)*64;
  int r16 = l&15, kq = l>>4;
  v4f acc[4][4] = {};
  int t4 = tid>>2, c8 = (tid&3)*8;
  const unsigned short* Ag = A  + (size_t)(m0 + t4)*K + c8;
  const unsigned short* Bg = Bt + (size_t)(n0 + t4)*K + c8;
  char* AsB = (char*)&As[0][0] + w*1024;
  char* BsB = (char*)&Bs[0][0] + w*1024;
  for (int kb=0; kb<K; kb+=32){
    __syncthreads();
    gll16(Ag + kb,                 AsB);
    gll16(Ag + (size_t)64*K + kb,  AsB + 4096);
    gll16(Bg + kb,                 BsB);
    gll16(Bg + (size_t)64*K + kb,  BsB + 4096);
    __syncthreads();
    v8s a[4], b[4];
    #pragma unroll
    for (int mi=0;mi<4;mi++) a[mi] = *(const v8s*)&As[wm+mi*16+r16][kq*8];
    #pragma unroll
    for (int ni=0;ni<4;ni++) b[ni] = *(const v8s*)&Bs[wn+ni*16+r16][kq*8];
    #pragma unroll
    for (int mi=0;mi<4;mi++)
      #pragma unroll
      for (int ni=0;ni<4;ni++)
        acc[mi][ni] = MFMA16(a[mi], b[ni], acc[mi][ni]);
  }
  #pragma unroll
  for (int mi=0;mi<4;mi++){
    #pragma unroll
    for (int ni=0;ni<4;ni++){
      int col = n0 + wn + ni*16 + r16;
      float bv = bias[col];
      #pragma unroll
      for (int r=0;r<4;r++){
        int row = m0 + wm + mi*16 + kq*4 + r;
        float t = acc[mi][ni][r] + bv;
        if (MODE==2 || MODE==3) t = gelu_exact(t);
        if (MODE==2) outb[(size_t)row*N + col] = f2b(t);
        else         outf[(size_t)row*N + col] = t + res[(size_t)row*N + col];
      }
    }
  }
}

// ---------------- flash attention: block=(b,h,64 q-rows), 4 waves x 16 rows -
__global__ __launch_bounds__(256) void attn_kernel(
    const unsigned short* __restrict__ Q, const unsigned short* __restrict__ Kb,
    const unsigned short* __restrict__ Vb, const int* __restrict__ mask,
    const unsigned char* __restrict__ flags, unsigned short* __restrict__ out)
{
  const int S = 2048, D = 1024;
  __shared__ unsigned short Ks[64][72];
  __shared__ unsigned short Vt[64][72];
  __shared__ unsigned short Ps[4][16][72];
  int bid = blockIdx.x;            // b*512 + h*32 + qt  -> decode below
  int qt = bid & 31;
  int bh = bid >> 5;
  int b = bh >> 4, h = bh & 15;
  int tid = threadIdx.x, w = tid>>6, l = tid&63;
  int r16 = l&15, kq = l>>4;
  size_t base = (size_t)b*S*D + h*64;
  const unsigned short* Qp = Q  + base;
  const unsigned short* Kp = Kb + base;
  const unsigned short* Vp = Vb + base;
  int qrow0 = qt*64 + w*16;
  v8s qf[2];
  #pragma unroll
  for (int ks=0;ks<2;ks++)
    qf[ks] = *(const v8s*)(Qp + (size_t)(qrow0+r16)*D + ks*32 + kq*8);
  float m_run[4], l_run[4];
  v4f o[4] = {};
  #pragma unroll
  for (int r=0;r<4;r++){ m_run[r] = -1e30f; l_run[r] = 0.0f; }
  const int* mp = mask + (size_t)b*S*S;
  const unsigned char* fl = flags + (size_t)(b*32 + qt)*32;
  int sr = tid>>3, sc = (tid&7)*8;
  for (int kt=0; kt<32; kt++){
    int kt64 = kt*64;
    v4u k0 = *(const v4u*)(Kp + (size_t)(kt64+sr   )*D + sc);
    v4u k1 = *(const v4u*)(Kp + (size_t)(kt64+sr+32)*D + sc);
    v4u v0 = *(const v4u*)(Vp + (size_t)(kt64+sr   )*D + sc);
    v4u v1 = *(const v4u*)(Vp + (size_t)(kt64+sr+32)*D + sc);
    __syncthreads();
    *(v4u*)&Ks[sr   ][sc] = k0;
    *(v4u*)&Ks[sr+32][sc] = k1;
    {
      const unsigned short* p0 = (const unsigned short*)&v0;
      const unsigned short* p1 = (const unsigned short*)&v1;
      #pragma unroll
      for (int j=0;j<8;j++){ Vt[sc+j][sr] = p0[j]; Vt[sc+j][sr+32] = p1[j]; }
    }
    __syncthreads();
    v4f s[4] = {};
    #pragma unroll
    for (int ks=0;ks<2;ks++){
      v8s kf[4];
      #pragma unroll
      for (int nj=0;nj<4;nj++) kf[nj] = *(const v8s*)&Ks[nj*16+r16][ks*32+kq*8];
      #pragma unroll
      for (int nj=0;nj<4;nj++)
        s[nj] = MFMA16(qf[ks], kf[nj], s[nj]);
    }
    if (!fl[kt]){   // general-mask slow path (not taken for all-ones mask)
      #pragma unroll
      for (int nj=0;nj<4;nj++){
        int kcol = kt64 + nj*16 + r16;
        #pragma unroll
        for (int r=0;r<4;r++){
          int qrow = qrow0 + kq*4 + r;
          if (mp[(size_t)qrow*S + kcol] == 0) s[nj][r] = -3.0e38f;
        }
      }
    }
    // online softmax in exp2 domain (scores pre-scaled by 0.125*log2e via Q)
    #pragma unroll
    for (int r=0;r<4;r++){
      float t = fmaxf(fmaxf(s[0][r], s[1][r]), fmaxf(s[2][r], s[3][r]));
      t = fmaxf(t, __shfl_xor(t,1));
      t = fmaxf(t, __shfl_xor(t,2));
      t = fmaxf(t, __shfl_xor(t,4));
      t = fmaxf(t, __shfl_xor(t,8));
      float mn = fmaxf(m_run[r], t);
      float corr = exp2f(m_run[r] - mn);
      m_run[r] = mn;
      float rs = 0.0f;
      #pragma unroll
      for (int nj=0;nj<4;nj++){
        float p = exp2f(s[nj][r] - mn);
        s[nj][r] = p;
        rs += p;
      }
      rs += __shfl_xor(rs,1); rs += __shfl_xor(rs,2);
      rs += __shfl_xor(rs,4); rs += __shfl_xor(rs,8);
      l_run[r] = l_run[r]*corr + rs;
      #pragma unroll
      for (int nj=0;nj<4;nj++) o[nj][r] *= corr;
    }
    // P -> LDS for PV A-fragments
    #pragma unroll
    for (int nj=0;nj<4;nj++)
      #pragma unroll
      for (int r=0;r<4;r++)
        Ps[w][kq*4+r][nj*16+r16] = f2b(s[nj][r]);
    // PV
    #pragma unroll
    for (int ks=0;ks<2;ks++){
      v8s pa = *(const v8s*)&Ps[w][r16][ks*32+kq*8];
      v8s vv[4];
      #pragma unroll
      for (int nj=0;nj<4;nj++) vv[nj] = *(const v8s*)&Vt[nj*16+r16][ks*32+kq*8];
      #pragma unroll
      for (int nj=0;nj<4;nj++)
        o[nj] = MFMA16(pa, vv[nj], o[nj]);
    }
  }
  #pragma unroll
  for (int r=0;r<4;r++){
    float invl = 1.0f / l_run[r];
    int qrow = qrow0 + kq*4 + r;
    #pragma unroll
    for (int nj=0;nj<4;nj++)
      out[(size_t)(b*S+qrow)*D + h*64 + nj*16 + r16] = f2b(o[nj][r]*invl);
  }
}

// ---------------- launcher ----------------
extern "C" void kernel_launch(void* const* d_in, const int* in_sizes, int n_in,
                              void* d_out, int out_size, void* d_ws, size_t ws_size,
                              hipStream_t stream)
{
  const int D=1024, DFF=2048, BS=4096;
  const float* x      = (const float*)d_in[0];
  const int*   mask   = (const int*)d_in[1];
  const float* alpha1 = (const float*)d_in[2];
  const float* bias1  = (const float*)d_in[3];
  const float* Wq     = (const float*)d_in[4];
  const float* bq     = (const float*)d_in[5];
  const float* Wk     = (const float*)d_in[6];
  const float* bk     = (const float*)d_in[7];
  const float* Wv     = (const float*)d_in[8];
  const float* bv     = (const float*)d_in[9];
  const float* Wo     = (const float*)d_in[10];
  const float* bo     = (const float*)d_in[11];
  const float* alpha2 = (const float*)d_in[12];
  const float* bias2  = (const float*)d_in[13];
  const float* W1     = (const float*)d_in[14];
  const float* b1     = (const float*)d_in[15];
  const float* W2     = (const float*)d_in[16];
  const float* b2     = (const float*)d_in[17];
  float* outp = (float*)d_out;

  char* ws = (char*)d_ws;
  size_t off = 0;
  auto alloc = [&](size_t bytes){ void* p = ws+off; off += (bytes+255)&~(size_t)255; return p; };
  unsigned short* x2b    = (unsigned short*)alloc((size_t)BS*D*2);
  unsigned short* qB     = (unsigned short*)alloc((size_t)BS*D*2);
  unsigned short* kB     = (unsigned short*)alloc((size_t)BS*D*2);
  unsigned short* vB     = (unsigned short*)alloc((size_t)BS*D*2);
  unsigned short* attnB  = (unsigned short*)alloc((size_t)BS*D*2);
  unsigned short* h1     = (unsigned short*)alloc((size_t)BS*DFF*2);
  float*          xres   = (float*)alloc((size_t)BS*D*4);
  unsigned short* wqkvT  = (unsigned short*)alloc((size_t)3*D*D*2);
  unsigned short* woT    = (unsigned short*)alloc((size_t)D*D*2);
  unsigned short* w1T    = (unsigned short*)alloc((size_t)D*DFF*2);
  unsigned short* w2T    = (unsigned short*)alloc((size_t)DFF*D*2);
  unsigned char*  flg    = (unsigned char*)alloc(2048);

  dim3 tb(32,8);
  transpose_f2b<<<dim3(D/32,  D/32 ), tb, 0, stream>>>(Wq, wqkvT,           D, D);
  transpose_f2b<<<dim3(D/32,  D/32 ), tb, 0, stream>>>(Wk, wqkvT + D*D,     D, D);
  transpose_f2b<<<dim3(D/32,  D/32 ), tb, 0, stream>>>(Wv, wqkvT + 2*D*D,   D, D);
  transpose_f2b<<<dim3(D/32,  D/32 ), tb, 0, stream>>>(Wo, woT, D, D);
  transpose_f2b<<<dim3(DFF/32,D/32 ), tb, 0, stream>>>(W1, w1T, D, DFF);
  transpose_f2b<<<dim3(D/32,  DFF/32), tb, 0, stream>>>(W2, w2T, DFF, D);

  mask_flags<<<2048, 256, 0, stream>>>(mask, flg);
  ln_kernel<<<BS, 256, 0, stream>>>(x, alpha1, bias1, x2b);

  gemm_qkv<<<dim3(BS/128, 24), 256, 0, stream>>>(x2b, wqkvT, bq, bk, bv, qB, kB, vB);

  attn_kernel<<<1024, 256, 0, stream>>>(qB, kB, vB, mask, flg, attnB);

  gemm_bt<1><<<dim3(BS/128, D/128), 256, 0, stream>>>(attnB, woT, bo, x, nullptr, xres, BS, D, D);

  ln_kernel<<<BS, 256, 0, stream>>>(xres, alpha2, bias2, x2b);

  gemm_bt<2><<<dim3(BS/128, DFF/128), 256, 0, stream>>>(x2b, w1T, b1, nullptr, h1, nullptr, BS, DFF, D);
  gemm_bt<3><<<dim3(BS/128, D/128), 256, 0, stream>>>(h1, w2T, b2, xres, nullptr, outp, BS, D, DFF);
}